// Round 6
// baseline (872.663 us; speedup 1.0000x reference)
//
#include <hip/hip_runtime.h>
#include <hip/hip_bf16.h>
#include <math.h>

#define NODES 50000
#define EDGES 800000
#define EP    850000      // EDGES + NODES self loops
#define INCH  64
#define HIDD  96
#define NHEAD 4
#define CHD   24
#define NLAY  4
#define NGRF  1024
#define BNEPS 1e-5f
#define NB    49          // ceil(NODES/1024)
#define NEGBIG (-1.0e30f) // finite -inf sentinel: avoids NaN from exp(-inf - -inf)

__device__ __forceinline__ float elu1(float v) { return v > 0.f ? v : __expf(v) - 1.f; }

__device__ __forceinline__ unsigned short f2bf(float f) {   // RNE, matches HW
    unsigned u = __float_as_uint(f);
    return (unsigned short)((u + 0x7fffu + ((u >> 16) & 1u)) >> 16);
}

__device__ __forceinline__ float bnorm(float a, const float* __restrict__ bg,
                                       const float* __restrict__ rm, const float* __restrict__ rv,
                                       const float* __restrict__ gamma, const float* __restrict__ beta,
                                       int ch) {
    float hn = a + bg[ch];
    return (hn - rm[ch]) / sqrtf(rv[ch] + BNEPS) * gamma[ch] + beta[ch];
}

__device__ __forceinline__ void edge_sd(int e, const int* __restrict__ S,
                                        const int* __restrict__ D, int& s, int& d) {
    if (e < EDGES) { s = S[e]; d = D[e]; } else { s = e - EDGES; d = s; }
}

// ---------------- CSR build (once per call; graph is layer-invariant) ----------------

__global__ __launch_bounds__(256) void k_count(const int* __restrict__ S, const int* __restrict__ D,
                                               int* __restrict__ cnt) {
    int e = blockIdx.x * blockDim.x + threadIdx.x;
    if (e >= EP) return;
    int s, d; edge_sd(e, S, D, s, d);
    atomicAdd(&cnt[d], 1);
}

__global__ __launch_bounds__(1024) void k_scan1(const int* __restrict__ cnt,
                                                int* __restrict__ off, int* __restrict__ bsum) {
    __shared__ int sd[1024];
    int t = threadIdx.x;
    int i = blockIdx.x * 1024 + t;
    int v = (i < NODES) ? cnt[i] : 0;
    sd[t] = v; __syncthreads();
    for (int o = 1; o < 1024; o <<= 1) {
        int tv = (t >= o) ? sd[t - o] : 0;
        __syncthreads();
        sd[t] += tv; __syncthreads();
    }
    if (i < NODES) off[i] = sd[t] - v;           // exclusive within block
    if (t == 1023) bsum[blockIdx.x] = sd[1023];
}

__global__ void k_scan2(int* __restrict__ bsum, int* __restrict__ off) {
    if (threadIdx.x == 0 && blockIdx.x == 0) {
        int run = 0;
        for (int b = 0; b < NB; ++b) { int tv = bsum[b]; bsum[b] = run; run += tv; }
        off[NODES] = run;                        // == EP
    }
}

__global__ __launch_bounds__(1024) void k_scan3(int* __restrict__ off, const int* __restrict__ bsum,
                                                int* __restrict__ cursor) {
    int i = blockIdx.x * 1024 + threadIdx.x;
    if (i >= NODES) return;
    int o = off[i] + bsum[blockIdx.x];
    off[i] = o;
    cursor[i] = o;
}

__global__ __launch_bounds__(256) void k_scatter(const int* __restrict__ S, const int* __restrict__ D,
                                                 int* __restrict__ cursor, int* __restrict__ csr_src) {
    int e = blockIdx.x * blockDim.x + threadIdx.x;
    if (e >= EP) return;
    int s, d; edge_sd(e, S, D, s, d);
    int pos = atomicAdd(&cursor[d], 1);
    csr_src[pos] = s;
}

// ---------------- dense node kernels ----------------

// h0 = elu(x @ W_in + b_in). W staged in LDS; lane=node, wave-uniform channel group.
__global__ __launch_bounds__(256) void k_in_proj(const float* __restrict__ x,
                                                 const float* __restrict__ W,
                                                 const float* __restrict__ b,
                                                 float* __restrict__ h) {
    __shared__ float Wl[INCH * HIDD];   // 24 KB
    int tid = threadIdx.x;
    for (int i = tid; i < INCH * HIDD; i += 256) Wl[i] = W[i];
    __syncthreads();

    int node = blockIdx.x * 64 + (tid & 63);
    if (node >= NODES) return;
    int cbase = (tid >> 6) * CHD;       // 0,24,48,72 (wave-uniform)
    const float* __restrict__ xr = x + (size_t)node * INCH;

    float acc[CHD];
#pragma unroll
    for (int j = 0; j < CHD; ++j) acc[j] = b[cbase + j];

#pragma unroll
    for (int k0 = 0; k0 < INCH; k0 += 4) {
        float4 xv = *(const float4*)(xr + k0);
        const float xvv[4] = {xv.x, xv.y, xv.z, xv.w};
#pragma unroll
        for (int kk = 0; kk < 4; ++kk) {
#pragma unroll
            for (int j = 0; j < CHD; ++j)
                acc[j] = fmaf(xvv[kk], Wl[(k0 + kk) * HIDD + cbase + j], acc[j]);
        }
    }
    float* hrow = h + (size_t)node * HIDD + cbase;
#pragma unroll
    for (int j = 0; j < CHD; ++j) hrow[j] = elu1(acc[j]);
}

// hp(bf16-packed) = h @ Wg[i]; fused per-head attention dots (cgroup == head).
__global__ __launch_bounds__(256) void k_proj(const float* __restrict__ h,
                                              const float* __restrict__ W,
                                              const float* __restrict__ asrc,
                                              const float* __restrict__ adst,
                                              unsigned* __restrict__ hpb,   // [N][48] packed bf16x2
                                              float* __restrict__ as_,
                                              float* __restrict__ ad_) {
    int node = blockIdx.x * 64 + (threadIdx.x & 63);
    if (node >= NODES) return;
    int head = __builtin_amdgcn_readfirstlane(threadIdx.x >> 6);   // 0..3
    int cbase = head * CHD;
    const float* __restrict__ Wc = W + cbase;
    const float* __restrict__ hr = h + (size_t)node * HIDD;

    float acc[CHD] = {};
#pragma unroll
    for (int k0 = 0; k0 < HIDD; k0 += 4) {
        float4 hv = *(const float4*)(hr + k0);
        const float hvv[4] = {hv.x, hv.y, hv.z, hv.w};
#pragma unroll
        for (int kk = 0; kk < 4; ++kk) {
#pragma unroll
            for (int j = 0; j < CHD; ++j)
                acc[j] = fmaf(hvv[kk], Wc[(k0 + kk) * HIDD + j], acc[j]);
        }
    }
    unsigned* orow = hpb + ((size_t)node * HIDD + cbase) / 2;
#pragma unroll
    for (int j = 0; j < CHD; j += 2)
        orow[j / 2] = (unsigned)f2bf(acc[j]) | ((unsigned)f2bf(acc[j + 1]) << 16);

    const float* __restrict__ s = asrc + head * CHD;
    const float* __restrict__ d = adst + head * CHD;
    float sa = 0.f, da = 0.f;
#pragma unroll
    for (int j = 0; j < CHD; ++j) { sa = fmaf(acc[j], s[j], sa); da = fmaf(acc[j], d[j], da); }
    as_[node * NHEAD + head] = sa;
    ad_[node * NHEAD + head] = da;
}

// ---------------- fused edge phase ----------------
// pass 1: online per-head max+sum. pass 2: 16-edge chunks, alpha computed once per
// (edge,head) by lanes (slot,head), broadcast via shfl; 48 lanes gather bf16x2 hp rows.

__global__ __launch_bounds__(256) void k_edge(const int* __restrict__ off,
                                              const int* __restrict__ csr,
                                              const float* __restrict__ as_,
                                              const float* __restrict__ ad_,
                                              const unsigned* __restrict__ hpb,
                                              const float* __restrict__ bg,
                                              const float* __restrict__ gamma,
                                              const float* __restrict__ beta,
                                              const float* __restrict__ rm,
                                              const float* __restrict__ rv,
                                              float* __restrict__ h,
                                              const int* __restrict__ batch,
                                              float* __restrict__ pooled) {
    int node = blockIdx.x * 4 + (threadIdx.x >> 6);
    if (node >= NODES) return;
    int lane = threadIdx.x & 63;
    int beg = off[node], end = off[node + 1];

    int hd = lane & 3, slot = lane >> 2;        // lane = slot*4 + hd
    float adv = ad_[node * NHEAD + hd];

    // ---- pass 1: online max+sum per head ----
    float m = NEGBIG, z = 0.f;
    for (int i = beg + slot; i < end; i += 16) {
        float ev = as_[csr[i] * NHEAD + hd] + adv;
        ev = ev > 0.f ? ev : 0.2f * ev;
        float mn = fmaxf(m, ev);
        z = z * __expf(m - mn) + __expf(ev - mn);
        m = mn;
    }
#pragma unroll
    for (int o = 4; o < 64; o <<= 1) {
        float mo = __shfl_xor(m, o), zo = __shfl_xor(z, o);
        float mn = fmaxf(m, mo);
        z = z * __expf(m - mn) + zo * __expf(mo - mn);
        m = mn;
    }
    float iz = 1.f / (z + 1e-16f);   // every lane: stats for head lane&3

    // ---- pass 2: chunked alpha + gather ----
    const int hh = (lane < 48) ? (lane / 12) : 0;   // head of channel pair (2*lane, 2*lane+1)
    float acc0 = 0.f, acc1 = 0.f;
    for (int c0 = beg; c0 < end; c0 += 16) {
        int i = c0 + slot;
        int sreg = 0; float av = 0.f;
        if (i < end) {
            sreg = csr[i];
            float ev = as_[sreg * NHEAD + hd] + adv;
            ev = ev > 0.f ? ev : 0.2f * ev;
            av = __expf(ev - m) * iz;            // alpha(edge i, head hd)
        }
        int cnt = min(16, end - c0);
        for (int j = 0; j < cnt; ++j) {
            int   sv = __shfl(sreg, j * 4);
            float al = __shfl(av,   j * 4 + hh);
            if (lane < 48) {
                unsigned u = hpb[(size_t)sv * (HIDD / 2) + lane];
                acc0 = fmaf(__uint_as_float(u << 16),         al, acc0);
                acc1 = fmaf(__uint_as_float(u & 0xffff0000u), al, acc1);
            }
        }
    }

    if (lane < 48) {
        int ch0 = 2 * lane, ch1 = ch0 + 1;
        float hn0 = bnorm(acc0, bg, rm, rv, gamma, beta, ch0);
        float hn1 = bnorm(acc1, bg, rm, rv, gamma, beta, ch1);
        float2 hv = *(float2*)(h + (size_t)node * HIDD + ch0);
        hv.x += elu1(hn0);
        hv.y += elu1(hn1);
        *(float2*)(h + (size_t)node * HIDD + ch0) = hv;
        int gi = batch[node] * HIDD;
        atomicAdd(&pooled[gi + ch0], hv.x);
        atomicAdd(&pooled[gi + ch1], hv.y);
    }
}

// ---------------- per-graph MLP head ----------------

__global__ __launch_bounds__(128) void k_head(const float* __restrict__ pooled,
                                              const float* __restrict__ Wjk, const float* __restrict__ bjk,
                                              const float* __restrict__ Wh1, const float* __restrict__ bh1,
                                              const float* __restrict__ Wh2, const float* __restrict__ bh2,
                                              float* __restrict__ out) {
    __shared__ float pin[NLAY * HIDD];
    __shared__ float z1[HIDD];
    __shared__ float z2[HIDD];
    int g = blockIdx.x, tid = threadIdx.x;
    for (int idx = tid; idx < NLAY * HIDD; idx += blockDim.x) {
        int l = idx / HIDD, c = idx % HIDD;
        pin[idx] = pooled[(size_t)l * NGRF * HIDD + (size_t)g * HIDD + c];
    }
    __syncthreads();
    for (int c = tid; c < HIDD; c += blockDim.x) {
        float a = bjk[c];
        for (int k = 0; k < NLAY * HIDD; ++k) a = fmaf(pin[k], Wjk[k * HIDD + c], a);
        z1[c] = elu1(a);
    }
    __syncthreads();
    for (int c = tid; c < HIDD; c += blockDim.x) {
        float a = bh1[c];
#pragma unroll
        for (int k = 0; k < HIDD; ++k) a = fmaf(z1[k], Wh1[k * HIDD + c], a);
        z2[c] = fmaxf(a, 0.f);
    }
    __syncthreads();
    if (tid < 64) {
        float a = 0.f;
        for (int k = tid; k < HIDD; k += 64) a = fmaf(z2[k], Wh2[k], a);
#pragma unroll
        for (int o = 32; o > 0; o >>= 1) a += __shfl_down(a, o);
        if (tid == 0) out[g] = a + bh2[0];
    }
}

extern "C" void kernel_launch(void* const* d_in, const int* in_sizes, int n_in,
                              void* d_out, int out_size, void* d_ws, size_t ws_size,
                              hipStream_t stream) {
    const float* x     = (const float*)d_in[0];
    const int*   ei    = (const int*)d_in[1];
    const int*   batch = (const int*)d_in[2];
    const float* W_in  = (const float*)d_in[3];
    const float* b_in  = (const float*)d_in[4];
    const float* Wg    = (const float*)d_in[5];
    const float* att_s = (const float*)d_in[6];
    const float* att_d = (const float*)d_in[7];
    const float* bg    = (const float*)d_in[8];
    const float* gamma = (const float*)d_in[9];
    const float* beta  = (const float*)d_in[10];
    const float* rm    = (const float*)d_in[11];
    const float* rv    = (const float*)d_in[12];
    const float* Wjk   = (const float*)d_in[13];
    const float* bjk   = (const float*)d_in[14];
    const float* Wh1   = (const float*)d_in[15];
    const float* bh1   = (const float*)d_in[16];
    const float* Wh2   = (const float*)d_in[17];
    const float* bh2   = (const float*)d_in[18];
    float* out = (float*)d_out;

    const int* S = ei;
    const int* Dd = ei + EDGES;

    // workspace layout
    float* ws = (float*)d_ws;
    float*    h      = ws;                               // N*96 f32
    float*    as_    = h    + (size_t)NODES * HIDD;      // N*4
    float*    ad_    = as_  + (size_t)NODES * NHEAD;     // N*4
    float*    pooled = ad_  + (size_t)NODES * NHEAD;     // L*G*96
    unsigned* hpb    = (unsigned*)(pooled + (size_t)NLAY * NGRF * HIDD); // N*48 (bf16x2)
    int*      off    = (int*)(hpb + (size_t)NODES * (HIDD / 2));  // N+1
    int*      cursor = off    + NODES + 1;               // N
    int*      csr    = cursor + NODES;                   // EP
    int*      cnt    = csr    + EP;                      // N
    int*      bsum   = cnt    + NODES;                   // NB

    hipMemsetAsync(pooled, 0, sizeof(float) * NLAY * NGRF * HIDD, stream);
    hipMemsetAsync(cnt, 0, sizeof(int) * NODES, stream);

    const int TB = 256;
    int gE    = (EP + TB - 1) / TB;
    int gTile = (NODES + 63) / 64;   // 782 blocks, 64 nodes each
    int gWave = NODES / 4;           // 12500

    // CSR build (graph is identical across layers)
    k_count<<<gE, TB, 0, stream>>>(S, Dd, cnt);
    k_scan1<<<NB, 1024, 0, stream>>>(cnt, off, bsum);
    k_scan2<<<1, 64, 0, stream>>>(bsum, off);
    k_scan3<<<NB, 1024, 0, stream>>>(off, bsum, cursor);
    k_scatter<<<gE, TB, 0, stream>>>(S, Dd, cursor, csr);

    k_in_proj<<<gTile, TB, 0, stream>>>(x, W_in, b_in, h);

    for (int i = 0; i < NLAY; ++i) {
        k_proj<<<gTile, TB, 0, stream>>>(h, Wg + (size_t)i * HIDD * HIDD,
                                         att_s + i * NHEAD * CHD, att_d + i * NHEAD * CHD,
                                         hpb, as_, ad_);
        k_edge<<<gWave, TB, 0, stream>>>(off, csr, as_, ad_, hpb,
                                         bg + i * HIDD, gamma + i * HIDD, beta + i * HIDD,
                                         rm + i * HIDD, rv + i * HIDD, h, batch,
                                         pooled + (size_t)i * NGRF * HIDD);
    }

    k_head<<<NGRF, 128, 0, stream>>>(pooled, Wjk, bjk, Wh1, bh1, Wh2, bh2, out);
}

// Round 7
// 601.360 us; speedup vs baseline: 1.4511x; 1.4511x over previous
//
#include <hip/hip_runtime.h>
#include <hip/hip_bf16.h>
#include <math.h>

#define NODES 50000
#define EDGES 800000
#define EP    850000      // EDGES + NODES self loops
#define INCH  64
#define HIDD  96
#define NHEAD 4
#define CHD   24
#define NLAY  4
#define NGRF  1024
#define BNEPS 1e-5f
#define NB    49          // ceil(NODES/1024)
#define NEGBIG (-1.0e30f) // finite -inf sentinel: avoids NaN from exp(-inf - -inf)

__device__ __forceinline__ float elu1(float v) { return v > 0.f ? v : __expf(v) - 1.f; }

__device__ __forceinline__ unsigned short f2bf(float f) {   // RNE, matches HW
    unsigned u = __float_as_uint(f);
    return (unsigned short)((u + 0x7fffu + ((u >> 16) & 1u)) >> 16);
}

__device__ __forceinline__ float bnorm(float a, const float* __restrict__ bg,
                                       const float* __restrict__ rm, const float* __restrict__ rv,
                                       const float* __restrict__ gamma, const float* __restrict__ beta,
                                       int ch) {
    float hn = a + bg[ch];
    return (hn - rm[ch]) / sqrtf(rv[ch] + BNEPS) * gamma[ch] + beta[ch];
}

__device__ __forceinline__ void edge_sd(int e, const int* __restrict__ S,
                                        const int* __restrict__ D, int& s, int& d) {
    if (e < EDGES) { s = S[e]; d = D[e]; } else { s = e - EDGES; d = s; }
}

// ---------------- CSR build (once per call; graph is layer-invariant) ----------------

__global__ __launch_bounds__(256) void k_count(const int* __restrict__ S, const int* __restrict__ D,
                                               int* __restrict__ cnt) {
    int e = blockIdx.x * blockDim.x + threadIdx.x;
    if (e >= EP) return;
    int s, d; edge_sd(e, S, D, s, d);
    atomicAdd(&cnt[d], 1);
}

__global__ __launch_bounds__(1024) void k_scan1(const int* __restrict__ cnt,
                                                int* __restrict__ off, int* __restrict__ bsum) {
    __shared__ int sd[1024];
    int t = threadIdx.x;
    int i = blockIdx.x * 1024 + t;
    int v = (i < NODES) ? cnt[i] : 0;
    sd[t] = v; __syncthreads();
    for (int o = 1; o < 1024; o <<= 1) {
        int tv = (t >= o) ? sd[t - o] : 0;
        __syncthreads();
        sd[t] += tv; __syncthreads();
    }
    if (i < NODES) off[i] = sd[t] - v;           // exclusive within block
    if (t == 1023) bsum[blockIdx.x] = sd[1023];
}

__global__ void k_scan2(int* __restrict__ bsum, int* __restrict__ off) {
    if (threadIdx.x == 0 && blockIdx.x == 0) {
        int run = 0;
        for (int b = 0; b < NB; ++b) { int tv = bsum[b]; bsum[b] = run; run += tv; }
        off[NODES] = run;                        // == EP
    }
}

__global__ __launch_bounds__(1024) void k_scan3(int* __restrict__ off, const int* __restrict__ bsum,
                                                int* __restrict__ cursor) {
    int i = blockIdx.x * 1024 + threadIdx.x;
    if (i >= NODES) return;
    int o = off[i] + bsum[blockIdx.x];
    off[i] = o;
    cursor[i] = o;
}

__global__ __launch_bounds__(256) void k_scatter(const int* __restrict__ S, const int* __restrict__ D,
                                                 int* __restrict__ cursor, int* __restrict__ csr_src) {
    int e = blockIdx.x * blockDim.x + threadIdx.x;
    if (e >= EP) return;
    int s, d; edge_sd(e, S, D, s, d);
    int pos = atomicAdd(&cursor[d], 1);
    csr_src[pos] = s;
}

// ---------------- dense node kernels ----------------

// h0 = elu(x @ W_in + b_in). W staged in LDS; lane=node, wave-uniform channel group.
__global__ __launch_bounds__(256) void k_in_proj(const float* __restrict__ x,
                                                 const float* __restrict__ W,
                                                 const float* __restrict__ b,
                                                 float* __restrict__ h) {
    __shared__ float Wl[INCH * HIDD];   // 24 KB
    int tid = threadIdx.x;
    for (int i = tid; i < INCH * HIDD / 4; i += 256)
        ((float4*)Wl)[i] = ((const float4*)W)[i];
    __syncthreads();

    int node = blockIdx.x * 64 + (tid & 63);
    if (node >= NODES) return;
    int cbase = (tid >> 6) * CHD;       // 0,24,48,72 (wave-uniform)
    const float* __restrict__ xr = x + (size_t)node * INCH;

    float acc[CHD];
#pragma unroll
    for (int j = 0; j < CHD; ++j) acc[j] = b[cbase + j];

    for (int k0 = 0; k0 < INCH; k0 += 4) {
        float4 xv = *(const float4*)(xr + k0);
        const float xvv[4] = {xv.x, xv.y, xv.z, xv.w};
#pragma unroll
        for (int kk = 0; kk < 4; ++kk) {
#pragma unroll
            for (int j4 = 0; j4 < CHD; j4 += 4) {
                float4 wv = *(const float4*)(&Wl[(k0 + kk) * HIDD + cbase + j4]);
                acc[j4 + 0] = fmaf(xvv[kk], wv.x, acc[j4 + 0]);
                acc[j4 + 1] = fmaf(xvv[kk], wv.y, acc[j4 + 1]);
                acc[j4 + 2] = fmaf(xvv[kk], wv.z, acc[j4 + 2]);
                acc[j4 + 3] = fmaf(xvv[kk], wv.w, acc[j4 + 3]);
            }
        }
    }
    float* hrow = h + (size_t)node * HIDD + cbase;
#pragma unroll
    for (int j = 0; j < CHD; ++j) hrow[j] = elu1(acc[j]);
}

// hp(bf16-packed) = h @ Wg[i]; fused per-head attention dots (cgroup == head).
// Wg staged in LDS (36 KB) -> uniform-address broadcast ds_read_b128, no s_load serialization.
__global__ __launch_bounds__(256) void k_proj(const float* __restrict__ h,
                                              const float* __restrict__ W,
                                              const float* __restrict__ asrc,
                                              const float* __restrict__ adst,
                                              unsigned* __restrict__ hpb,   // [N][48] packed bf16x2
                                              float* __restrict__ as_,
                                              float* __restrict__ ad_) {
    __shared__ float Wl[HIDD * HIDD];   // 36 KB
    int tid = threadIdx.x;
    for (int i = tid; i < HIDD * HIDD / 4; i += 256)
        ((float4*)Wl)[i] = ((const float4*)W)[i];
    __syncthreads();

    int node = blockIdx.x * 64 + (tid & 63);
    if (node >= NODES) return;
    int head = tid >> 6;                 // 0..3 (wave-uniform)
    int cbase = head * CHD;
    const float* __restrict__ hr = h + (size_t)node * HIDD;

    float acc[CHD] = {};
    for (int k0 = 0; k0 < HIDD; k0 += 4) {
        float4 hv = *(const float4*)(hr + k0);
        const float hvv[4] = {hv.x, hv.y, hv.z, hv.w};
#pragma unroll
        for (int kk = 0; kk < 4; ++kk) {
#pragma unroll
            for (int j4 = 0; j4 < CHD; j4 += 4) {
                float4 wv = *(const float4*)(&Wl[(k0 + kk) * HIDD + cbase + j4]);
                acc[j4 + 0] = fmaf(hvv[kk], wv.x, acc[j4 + 0]);
                acc[j4 + 1] = fmaf(hvv[kk], wv.y, acc[j4 + 1]);
                acc[j4 + 2] = fmaf(hvv[kk], wv.z, acc[j4 + 2]);
                acc[j4 + 3] = fmaf(hvv[kk], wv.w, acc[j4 + 3]);
            }
        }
    }
    unsigned* orow = hpb + (size_t)node * (HIDD / 2) + cbase / 2;
#pragma unroll
    for (int j = 0; j < CHD; j += 2)
        orow[j / 2] = (unsigned)f2bf(acc[j]) | ((unsigned)f2bf(acc[j + 1]) << 16);

    const float* __restrict__ s = asrc + head * CHD;
    const float* __restrict__ d = adst + head * CHD;
    float sa = 0.f, da = 0.f;
#pragma unroll
    for (int j = 0; j < CHD; ++j) { sa = fmaf(acc[j], s[j], sa); da = fmaf(acc[j], d[j], da); }
    as_[node * NHEAD + head] = sa;
    ad_[node * NHEAD + head] = da;
}

// ---------------- fused edge phase ----------------
// pass 1: online per-head max+sum. pass 2: 16-edge chunks, alpha computed once per
// (edge,head) by lanes (slot,head), broadcast via shfl; 48 lanes gather bf16x2 hp rows.
// Full chunks take an unrolled path so all 16 gathers issue concurrently (ILP).

__global__ __launch_bounds__(256) void k_edge(const int* __restrict__ off,
                                              const int* __restrict__ csr,
                                              const float* __restrict__ as_,
                                              const float* __restrict__ ad_,
                                              const unsigned* __restrict__ hpb,
                                              const float* __restrict__ bg,
                                              const float* __restrict__ gamma,
                                              const float* __restrict__ beta,
                                              const float* __restrict__ rm,
                                              const float* __restrict__ rv,
                                              float* __restrict__ h,
                                              const int* __restrict__ batch,
                                              float* __restrict__ pooled) {
    int node = blockIdx.x * 4 + (threadIdx.x >> 6);
    if (node >= NODES) return;
    int lane = threadIdx.x & 63;
    int beg = off[node], end = off[node + 1];

    int hd = lane & 3, slot = lane >> 2;        // lane = slot*4 + hd
    float adv = ad_[node * NHEAD + hd];

    // ---- pass 1: online max+sum per head ----
    float m = NEGBIG, z = 0.f;
    for (int i = beg + slot; i < end; i += 16) {
        float ev = as_[csr[i] * NHEAD + hd] + adv;
        ev = ev > 0.f ? ev : 0.2f * ev;
        float mn = fmaxf(m, ev);
        z = z * __expf(m - mn) + __expf(ev - mn);
        m = mn;
    }
#pragma unroll
    for (int o = 4; o < 64; o <<= 1) {
        float mo = __shfl_xor(m, o), zo = __shfl_xor(z, o);
        float mn = fmaxf(m, mo);
        z = z * __expf(m - mn) + zo * __expf(mo - mn);
        m = mn;
    }
    float iz = 1.f / (z + 1e-16f);   // every lane: stats for head lane&3

    // ---- pass 2: chunked alpha + gather ----
    const int hh = (lane < 48) ? (lane / 12) : 0;   // head of channel pair (2*lane, 2*lane+1)
    float acc0 = 0.f, acc1 = 0.f;
    int c0 = beg;
    for (; c0 + 16 <= end; c0 += 16) {              // full chunks: unrolled, max ILP
        int i = c0 + slot;
        int sreg = csr[i];
        float ev = as_[sreg * NHEAD + hd] + adv;
        ev = ev > 0.f ? ev : 0.2f * ev;
        float av = __expf(ev - m) * iz;
#pragma unroll
        for (int j = 0; j < 16; ++j) {
            int   sv = __shfl(sreg, j * 4);
            float al = __shfl(av,   j * 4 + hh);
            if (lane < 48) {
                unsigned u = hpb[(size_t)sv * (HIDD / 2) + lane];
                acc0 = fmaf(__uint_as_float(u << 16),         al, acc0);
                acc1 = fmaf(__uint_as_float(u & 0xffff0000u), al, acc1);
            }
        }
    }
    if (c0 < end) {                                  // tail chunk
        int i = c0 + slot;
        int sreg = 0; float av = 0.f;
        if (i < end) {
            sreg = csr[i];
            float ev = as_[sreg * NHEAD + hd] + adv;
            ev = ev > 0.f ? ev : 0.2f * ev;
            av = __expf(ev - m) * iz;
        }
        int cnt = end - c0;
        for (int j = 0; j < cnt; ++j) {
            int   sv = __shfl(sreg, j * 4);
            float al = __shfl(av,   j * 4 + hh);
            if (lane < 48) {
                unsigned u = hpb[(size_t)sv * (HIDD / 2) + lane];
                acc0 = fmaf(__uint_as_float(u << 16),         al, acc0);
                acc1 = fmaf(__uint_as_float(u & 0xffff0000u), al, acc1);
            }
        }
    }

    if (lane < 48) {
        int ch0 = 2 * lane, ch1 = ch0 + 1;
        float hn0 = bnorm(acc0, bg, rm, rv, gamma, beta, ch0);
        float hn1 = bnorm(acc1, bg, rm, rv, gamma, beta, ch1);
        float2 hv = *(float2*)(h + (size_t)node * HIDD + ch0);
        hv.x += elu1(hn0);
        hv.y += elu1(hn1);
        *(float2*)(h + (size_t)node * HIDD + ch0) = hv;
        int gi = batch[node] * HIDD;
        atomicAdd(&pooled[gi + ch0], hv.x);
        atomicAdd(&pooled[gi + ch1], hv.y);
    }
}

// ---------------- per-graph MLP head ----------------

__global__ __launch_bounds__(128) void k_head(const float* __restrict__ pooled,
                                              const float* __restrict__ Wjk, const float* __restrict__ bjk,
                                              const float* __restrict__ Wh1, const float* __restrict__ bh1,
                                              const float* __restrict__ Wh2, const float* __restrict__ bh2,
                                              float* __restrict__ out) {
    __shared__ float pin[NLAY * HIDD];
    __shared__ float z1[HIDD];
    __shared__ float z2[HIDD];
    int g = blockIdx.x, tid = threadIdx.x;
    for (int idx = tid; idx < NLAY * HIDD; idx += blockDim.x) {
        int l = idx / HIDD, c = idx % HIDD;
        pin[idx] = pooled[(size_t)l * NGRF * HIDD + (size_t)g * HIDD + c];
    }
    __syncthreads();
    for (int c = tid; c < HIDD; c += blockDim.x) {
        float a = bjk[c];
        for (int k = 0; k < NLAY * HIDD; ++k) a = fmaf(pin[k], Wjk[k * HIDD + c], a);
        z1[c] = elu1(a);
    }
    __syncthreads();
    for (int c = tid; c < HIDD; c += blockDim.x) {
        float a = bh1[c];
#pragma unroll
        for (int k = 0; k < HIDD; ++k) a = fmaf(z1[k], Wh1[k * HIDD + c], a);
        z2[c] = fmaxf(a, 0.f);
    }
    __syncthreads();
    if (tid < 64) {
        float a = 0.f;
        for (int k = tid; k < HIDD; k += 64) a = fmaf(z2[k], Wh2[k], a);
#pragma unroll
        for (int o = 32; o > 0; o >>= 1) a += __shfl_down(a, o);
        if (tid == 0) out[g] = a + bh2[0];
    }
}

extern "C" void kernel_launch(void* const* d_in, const int* in_sizes, int n_in,
                              void* d_out, int out_size, void* d_ws, size_t ws_size,
                              hipStream_t stream) {
    const float* x     = (const float*)d_in[0];
    const int*   ei    = (const int*)d_in[1];
    const int*   batch = (const int*)d_in[2];
    const float* W_in  = (const float*)d_in[3];
    const float* b_in  = (const float*)d_in[4];
    const float* Wg    = (const float*)d_in[5];
    const float* att_s = (const float*)d_in[6];
    const float* att_d = (const float*)d_in[7];
    const float* bg    = (const float*)d_in[8];
    const float* gamma = (const float*)d_in[9];
    const float* beta  = (const float*)d_in[10];
    const float* rm    = (const float*)d_in[11];
    const float* rv    = (const float*)d_in[12];
    const float* Wjk   = (const float*)d_in[13];
    const float* bjk   = (const float*)d_in[14];
    const float* Wh1   = (const float*)d_in[15];
    const float* bh1   = (const float*)d_in[16];
    const float* Wh2   = (const float*)d_in[17];
    const float* bh2   = (const float*)d_in[18];
    float* out = (float*)d_out;

    const int* S = ei;
    const int* Dd = ei + EDGES;

    // workspace layout
    float* ws = (float*)d_ws;
    float*    h      = ws;                               // N*96 f32
    float*    as_    = h    + (size_t)NODES * HIDD;      // N*4
    float*    ad_    = as_  + (size_t)NODES * NHEAD;     // N*4
    float*    pooled = ad_  + (size_t)NODES * NHEAD;     // L*G*96
    unsigned* hpb    = (unsigned*)(pooled + (size_t)NLAY * NGRF * HIDD); // N*48 (bf16x2)
    int*      off    = (int*)(hpb + (size_t)NODES * (HIDD / 2));  // N+1
    int*      cursor = off    + NODES + 1;               // N
    int*      csr    = cursor + NODES;                   // EP
    int*      cnt    = csr    + EP;                      // N
    int*      bsum   = cnt    + NODES;                   // NB

    hipMemsetAsync(pooled, 0, sizeof(float) * NLAY * NGRF * HIDD, stream);
    hipMemsetAsync(cnt, 0, sizeof(int) * NODES, stream);

    const int TB = 256;
    int gE    = (EP + TB - 1) / TB;
    int gTile = (NODES + 63) / 64;   // 782 blocks, 64 nodes each
    int gWave = NODES / 4;           // 12500

    // CSR build (graph is identical across layers)
    k_count<<<gE, TB, 0, stream>>>(S, Dd, cnt);
    k_scan1<<<NB, 1024, 0, stream>>>(cnt, off, bsum);
    k_scan2<<<1, 64, 0, stream>>>(bsum, off);
    k_scan3<<<NB, 1024, 0, stream>>>(off, bsum, cursor);
    k_scatter<<<gE, TB, 0, stream>>>(S, Dd, cursor, csr);

    k_in_proj<<<gTile, TB, 0, stream>>>(x, W_in, b_in, h);

    for (int i = 0; i < NLAY; ++i) {
        k_proj<<<gTile, TB, 0, stream>>>(h, Wg + (size_t)i * HIDD * HIDD,
                                         att_s + i * NHEAD * CHD, att_d + i * NHEAD * CHD,
                                         hpb, as_, ad_);
        k_edge<<<gWave, TB, 0, stream>>>(off, csr, as_, ad_, hpb,
                                         bg + i * HIDD, gamma + i * HIDD, beta + i * HIDD,
                                         rm + i * HIDD, rv + i * HIDD, h, batch,
                                         pooled + (size_t)i * NGRF * HIDD);
    }

    k_head<<<NGRF, 128, 0, stream>>>(pooled, Wjk, bjk, Wh1, bh1, Wh2, bh2, out);
}